// Round 30
// baseline (222.107 us; speedup 1.0000x reference)
//
#include <hip/hip_runtime.h>

#define N_NODES 100000
#define N_EDGES 1600000
#define IN_CH   128
#define HID     64
#define NG      256
#define CAP     64   // padded CSR slots per node
#define NXCD    8
#define XRANGE  (N_NODES / NXCD)        // 12500 nodes per range (exact)
#define NSLICE  32
#define PERSLICE (N_EDGES / NSLICE)     // 50000 edges per slice (exact; %2==0)
#define LINB    ((N_NODES + 63) / 64)   // 1563

typedef __attribute__((ext_vector_type(8))) short bf16x8;
typedef __attribute__((ext_vector_type(4))) float f32x4;

// ---- round-to-nearest-even f32 -> bf16 bits ----
__device__ __forceinline__ unsigned short f2bf(float f) {
    union { float f; unsigned u; } v; v.f = f;
    unsigned r = v.u + 0x7FFF + ((v.u >> 16) & 1);
    return (unsigned short)(r >> 16);
}
__device__ __forceinline__ float bfval(unsigned short h) {
    return __uint_as_float((unsigned)h << 16);
}
__device__ __forceinline__ unsigned int f2bf2(float lo, float hi) {
    return (unsigned int)f2bf(lo) | ((unsigned int)f2bf(hi) << 16);
}
__device__ __forceinline__ float bf_lo(unsigned int p) { return __uint_as_float(p << 16); }
__device__ __forceinline__ float bf_hi(unsigned int p) { return __uint_as_float(p & 0xFFFF0000u); }

// ---- W conversion to fragment-linear hi/lo bf16 ----
__global__ void k_wcvt(const float* __restrict__ W1, const float* __restrict__ W2,
                       unsigned short* __restrict__ W1hi, unsigned short* __restrict__ W1lo,
                       unsigned short* __restrict__ W2hi, unsigned short* __restrict__ W2lo) {
    int t = blockIdx.x * blockDim.x + threadIdx.x;
    if (t < 64 * IN_CH) {
        int e = t & 7, lane = (t >> 3) & 63, q = t >> 9;
        int kk = q >> 2, cb = q & 3, kg = lane >> 4, r = lane & 15;
        float v = W1[(kk * 32 + kg * 8 + e) * 64 + cb * 16 + r];
        unsigned short hh = f2bf(v);
        W1hi[t] = hh;
        W1lo[t] = f2bf(v - bfval(hh));
    } else if (t < 64 * IN_CH + 64 * HID) {
        int t2 = t - 64 * IN_CH;
        int e = t2 & 7, lane = (t2 >> 3) & 63, q = t2 >> 9;
        int kk = q >> 2, cb = q & 3, kg = lane >> 4, r = lane & 15;
        float v = W2[(kk * 32 + kg * 8 + e) * 64 + cb * 16 + r];
        unsigned short hh = f2bf(v);
        W2hi[t2] = hh;
        W2lo[t2] = f2bf(v - bfval(hh));
    }
}

// ---- phase A: per-(range,slice) LDS count of dst; per-edge pos via
// PER-ELEMENT byte stores (each edge owned by exactly one range block) ----
__global__ void __launch_bounds__(1024) k_cntA(const int* __restrict__ dst,
                                               int* __restrict__ cnt32,
                                               unsigned char* __restrict__ pos) {
    __shared__ int c[XRANGE];   // 50KB
    const int r = blockIdx.x & (NXCD - 1);
    const int s = blockIdx.x >> 3;
    const int lo = r * XRANGE;
    for (int j = threadIdx.x; j < XRANGE; j += 1024) c[j] = 0;
    __syncthreads();
    const int4* d4 = reinterpret_cast<const int4*>(dst + s * PERSLICE);
    unsigned char* pp = pos + s * PERSLICE;
    for (int q = threadIdx.x; q < PERSLICE / 4; q += 1024) {
        int4 v = d4[q];
        int t, p;
        t = v.x - lo;
        if ((unsigned)t < XRANGE) { p = atomicAdd(&c[t], 1); pp[q * 4 + 0] = (unsigned char)(p < 255 ? p : 255); }
        t = v.y - lo;
        if ((unsigned)t < XRANGE) { p = atomicAdd(&c[t], 1); pp[q * 4 + 1] = (unsigned char)(p < 255 ? p : 255); }
        t = v.z - lo;
        if ((unsigned)t < XRANGE) { p = atomicAdd(&c[t], 1); pp[q * 4 + 2] = (unsigned char)(p < 255 ? p : 255); }
        t = v.w - lo;
        if ((unsigned)t < XRANGE) { p = atomicAdd(&c[t], 1); pp[q * 4 + 3] = (unsigned char)(p < 255 ? p : 255); }
    }
    __syncthreads();
    int* outp = cnt32 + (long)s * N_NODES + lo;
    for (int j = threadIdx.x; j < XRANGE; j += 1024) outp[j] = c[j];
}

// ---- prep: per-node exclusive scan over 32 slice counts -> PACKED uchar
// off8[node][slice] (3.2MB, L2-resident in every XCD); deg, dinv, pad, bounds ----
__global__ void k_prep(const int* __restrict__ cnt32, unsigned char* __restrict__ off8,
                       int* __restrict__ deg, float* __restrict__ dinv,
                       int* __restrict__ col, const int* __restrict__ batch,
                       int* __restrict__ start) {
    int i = blockIdx.x * blockDim.x + threadIdx.x;
    if (i >= N_NODES) return;
    int run = 0;
    unsigned int w[8];
#pragma unroll
    for (int w8 = 0; w8 < 8; ++w8) {
        unsigned int word = 0;
#pragma unroll
        for (int b = 0; b < 4; ++b) {
            int s = w8 * 4 + b;
            int v = cnt32[(long)s * N_NODES + i];
            unsigned int rc = (unsigned int)(run < 255 ? run : 255);
            word |= rc << (8 * b);
            run += v;
        }
        w[w8] = word;
    }
    uint4* o4 = reinterpret_cast<uint4*>(off8 + (long)i * 32);
    o4[0] = (uint4){w[0], w[1], w[2], w[3]};
    o4[1] = (uint4){w[4], w[5], w[6], w[7]};

    deg[i] = run;
    dinv[i] = rsqrtf((float)run + 1.0f);
    int n = run < CAP ? run : CAP;
    int n16 = (n + 15) & ~15;
    int* crow = col + (long)i * CAP;
    int self32 = i * 32;
    for (int p = n; p < n16; ++p) crow[p] = self32;
    int b = batch[i];
    int prev = (i == 0) ? -1 : batch[i - 1];
    for (int g = prev + 1; g <= b; ++g) start[g] = i;
    if (i == N_NODES - 1)
        for (int g = b + 1; g <= NG; ++g) start[g] = N_NODES;
}

// ---- phase C v4: 2 edges/thread via 8B scalar nt loads; nt col stores
// (no read-for-ownership on partial lines) ----
__global__ void k_place(const int* __restrict__ src, const int* __restrict__ dst,
                        const unsigned char* __restrict__ pos,
                        const unsigned char* __restrict__ off8, int* __restrict__ col) {
    int q = blockIdx.x * blockDim.x + threadIdx.x;
    if (q >= N_EDGES / 2) return;
    unsigned long dw = __builtin_nontemporal_load(
        reinterpret_cast<const unsigned long*>(dst) + q);
    unsigned long uw = __builtin_nontemporal_load(
        reinterpret_cast<const unsigned long*>(src) + q);
    unsigned short pw = __builtin_nontemporal_load(
        reinterpret_cast<const unsigned short*>(pos) + q);
    int d0 = (int)(dw & 0xFFFFFFFFu), d1 = (int)(dw >> 32);
    int u0 = (int)(uw & 0xFFFFFFFFu), u1 = (int)(uw >> 32);
    int s = (q * 2) / PERSLICE;   // PERSLICE%2==0 -> both edges share slice
    int p0 = (int)off8[(long)d0 * 32 + s] + (int)(pw & 0xFF);
    int p1 = (int)off8[(long)d1 * 32 + s] + (int)(pw >> 8);
    if (p0 < CAP) __builtin_nontemporal_store(u0 * 32, &col[(long)d0 * CAP + p0]);
    if (p1 < CAP) __builtin_nontemporal_store(u1 * 32, &col[(long)d1 * CAP + p1]);
}

// ---- linear: MFMA GEMM, 32 nodes/wave, frag-linear W, K-split 2-way,
// scaled bf16 out. hs[i][j] = bf16( dinv[i] * sum_k x[i][k]*W[k][j] ) ----
template <int K>
__global__ void __launch_bounds__(256) k_linear(const float* __restrict__ x,
                                                const unsigned short* __restrict__ Whi,
                                                const unsigned short* __restrict__ Wlo,
                                                const float* __restrict__ dinv,
                                                unsigned short* __restrict__ hs) {
    __shared__ f32x4 red[2][64][8];
    const int tid  = threadIdx.x;
    const int wv   = tid >> 6;
    const int pair = wv >> 1;
    const int h    = wv & 1;
    const int lane = tid & 63;
    const int row16 = lane & 15;
    const int kg    = lane >> 4;
    const int n0 = (blockIdx.x * 2 + pair) * 32;
    const bool valid = (n0 < N_NODES);

    f32x4 acc[2][4];
#pragma unroll
    for (int bt = 0; bt < 2; ++bt)
#pragma unroll
        for (int cb = 0; cb < 4; ++cb) acc[bt][cb] = (f32x4){0.f, 0.f, 0.f, 0.f};

    const int NKK = K / 32;
    const int kkBeg = h * (NKK / 2);
    const int kkEnd = kkBeg + NKK / 2;

#pragma unroll
    for (int kk = kkBeg; kk < kkEnd; ++kk) {
        bf16x8 xhi0, xlo0, xhi1, xlo1;
        {
            int rr = n0 + row16;
            rr = rr < N_NODES ? rr : N_NODES - 1;
            const float* ap = x + (long)rr * K + kk * 32 + kg * 8;
            float4 b0 = *reinterpret_cast<const float4*>(ap);
            float4 b1 = *reinterpret_cast<const float4*>(ap + 4);
#define CVT(dsthi, dstlo, i, val) { unsigned short h_ = f2bf(val); dsthi[i] = (short)h_; \
                                    dstlo[i] = (short)f2bf((val) - bfval(h_)); }
            CVT(xhi0, xlo0, 0, b0.x) CVT(xhi0, xlo0, 1, b0.y)
            CVT(xhi0, xlo0, 2, b0.z) CVT(xhi0, xlo0, 3, b0.w)
            CVT(xhi0, xlo0, 4, b1.x) CVT(xhi0, xlo0, 5, b1.y)
            CVT(xhi0, xlo0, 6, b1.z) CVT(xhi0, xlo0, 7, b1.w)
        }
        {
            int rr = n0 + 16 + row16;
            rr = rr < N_NODES ? rr : N_NODES - 1;
            const float* ap = x + (long)rr * K + kk * 32 + kg * 8;
            float4 b0 = *reinterpret_cast<const float4*>(ap);
            float4 b1 = *reinterpret_cast<const float4*>(ap + 4);
            CVT(xhi1, xlo1, 0, b0.x) CVT(xhi1, xlo1, 1, b0.y)
            CVT(xhi1, xlo1, 2, b0.z) CVT(xhi1, xlo1, 3, b0.w)
            CVT(xhi1, xlo1, 4, b1.x) CVT(xhi1, xlo1, 5, b1.y)
            CVT(xhi1, xlo1, 6, b1.z) CVT(xhi1, xlo1, 7, b1.w)
#undef CVT
        }
#pragma unroll
        for (int cb = 0; cb < 4; ++cb) {
            long foff = (long)((kk * 4 + cb) * 64 + lane) * 8;
            bf16x8 wh = *reinterpret_cast<const bf16x8*>(Whi + foff);
            bf16x8 wl = *reinterpret_cast<const bf16x8*>(Wlo + foff);
            acc[0][cb] = __builtin_amdgcn_mfma_f32_16x16x32_bf16(wh, xhi0, acc[0][cb], 0, 0, 0);
            acc[0][cb] = __builtin_amdgcn_mfma_f32_16x16x32_bf16(wh, xlo0, acc[0][cb], 0, 0, 0);
            acc[0][cb] = __builtin_amdgcn_mfma_f32_16x16x32_bf16(wl, xhi0, acc[0][cb], 0, 0, 0);
            acc[1][cb] = __builtin_amdgcn_mfma_f32_16x16x32_bf16(wh, xhi1, acc[1][cb], 0, 0, 0);
            acc[1][cb] = __builtin_amdgcn_mfma_f32_16x16x32_bf16(wh, xlo1, acc[1][cb], 0, 0, 0);
            acc[1][cb] = __builtin_amdgcn_mfma_f32_16x16x32_bf16(wl, xhi1, acc[1][cb], 0, 0, 0);
        }
    }

    if (h == 1) {
#pragma unroll
        for (int bt = 0; bt < 2; ++bt)
#pragma unroll
            for (int cb = 0; cb < 4; ++cb) red[pair][lane][bt * 4 + cb] = acc[bt][cb];
    }
    __syncthreads();
    if (h == 0 && valid) {
#pragma unroll
        for (int bt = 0; bt < 2; ++bt) {
            int n = n0 + bt * 16 + row16;
            float d = dinv[n];
#pragma unroll
            for (int cb = 0; cb < 4; ++cb) {
                f32x4 a = acc[bt][cb];
                f32x4 b = red[pair][lane][bt * 4 + cb];
                uint2 p;
                p.x = f2bf2((a[0] + b[0]) * d, (a[1] + b[1]) * d);
                p.y = f2bf2((a[2] + b[2]) * d, (a[3] + b[3]) * d);
                *reinterpret_cast<uint2*>(&hs[(long)n * 64 + cb * 16 + kg * 4]) = p;
            }
        }
    }
}

// ---- gather: predication-free, col pre-scaled (*32), dense deg ----
__global__ void k_gather(const int* __restrict__ deg, const int* __restrict__ col,
                         const unsigned int* __restrict__ hs2,
                         const float* __restrict__ dinv, const float* __restrict__ bias,
                         float* __restrict__ out) {
    int t = blockIdx.x * blockDim.x + threadIdx.x;
    int lane = t & 63;
    int half = lane >> 5;
    int c2 = lane & 31;
    int i = ((t >> 6) << 1) + half;
    if (i >= N_NODES) return;
    const int4* crow4 = reinterpret_cast<const int4*>(col + (long)i * CAP);
    int n = deg[i];
    n = n < CAP ? n : CAP;
    int n16 = (n + 15) & ~15;
    const unsigned int* hsc = hs2 + c2;
    unsigned int self = hsc[(long)i * 32];
    float selfL = bf_lo(self), selfH = bf_hi(self);
    float aL = selfL, aH = selfH;

    for (int e0 = 0; e0 < n16; e0 += 16) {
        int4 q0 = crow4[(e0 >> 2) + 0];
        int4 q1 = crow4[(e0 >> 2) + 1];
        int4 q2 = crow4[(e0 >> 2) + 2];
        int4 q3 = crow4[(e0 >> 2) + 3];
        unsigned int v[16];
        v[0]  = hsc[(long)q0.x]; v[1]  = hsc[(long)q0.y];
        v[2]  = hsc[(long)q0.z]; v[3]  = hsc[(long)q0.w];
        v[4]  = hsc[(long)q1.x]; v[5]  = hsc[(long)q1.y];
        v[6]  = hsc[(long)q1.z]; v[7]  = hsc[(long)q1.w];
        v[8]  = hsc[(long)q2.x]; v[9]  = hsc[(long)q2.y];
        v[10] = hsc[(long)q2.z]; v[11] = hsc[(long)q2.w];
        v[12] = hsc[(long)q3.x]; v[13] = hsc[(long)q3.y];
        v[14] = hsc[(long)q3.z]; v[15] = hsc[(long)q3.w];
#pragma unroll
        for (int j = 0; j < 16; ++j) {
            aL += bf_lo(v[j]);
            aH += bf_hi(v[j]);
        }
    }
    float fE = (float)(n16 - n);
    aL = fmaf(-fE, selfL, aL);
    aH = fmaf(-fE, selfH, aH);

    float di = dinv[i];
    float vL = fmaf(di, aL, bias[2 * c2]);
    float vH = fmaf(di, aH, bias[2 * c2 + 1]);
    float2 o;
    o.x = vL > 0.f ? vL : 0.f;
    o.y = vH > 0.f ? vH : 0.f;
    *reinterpret_cast<float2*>(&out[(long)i * 64 + 2 * c2]) = o;
}

// ---- fused mean-pool + head MLP ----
__global__ void k_poolhead(const float* __restrict__ a, const int* __restrict__ start,
                           const float* __restrict__ Wc1, const float* __restrict__ bc1,
                           const float* __restrict__ Wc2, const float* __restrict__ bc2,
                           float* __restrict__ out) {
    __shared__ float partial[4][64];
    __shared__ float gvec[64];
    __shared__ float tvec[32];
    int g = blockIdx.x;
    int w = threadIdx.x >> 6;
    int j = threadIdx.x & 63;
    int s0 = start[g], s1 = start[g + 1];
    float acc = 0.f;
    for (int i = s0 + w; i < s1; i += 4)
        acc += a[(long)i * 64 + j];
    partial[w][j] = acc;
    __syncthreads();
    if (w == 0) {
        float c = (float)(s1 - s0);
        c = c > 1.f ? c : 1.f;
        gvec[j] = (partial[0][j] + partial[1][j] + partial[2][j] + partial[3][j]) / c;
    }
    __syncthreads();
    if (threadIdx.x < 32) {
        int jj = threadIdx.x;
        float acc2 = bc1[jj];
#pragma unroll 8
        for (int k = 0; k < 64; ++k) acc2 = fmaf(gvec[k], Wc1[k * 32 + jj], acc2);
        tvec[jj] = acc2 > 0.f ? acc2 : 0.f;
    }
    __syncthreads();
    if (threadIdx.x < 2) {
        int jj = threadIdx.x;
        float acc2 = bc2[jj];
#pragma unroll
        for (int k = 0; k < 32; ++k) acc2 = fmaf(tvec[k], Wc2[k * 2 + jj], acc2);
        out[g * 2 + jj] = acc2;
    }
}

extern "C" void kernel_launch(void* const* d_in, const int* in_sizes, int n_in,
                              void* d_out, int out_size, void* d_ws, size_t ws_size,
                              hipStream_t stream) {
    const float* x    = (const float*)d_in[0];
    const int*   ei   = (const int*)d_in[1];
    const int*   batch= (const int*)d_in[2];
    const float* W1   = (const float*)d_in[3];
    const float* b1   = (const float*)d_in[4];
    const float* W2   = (const float*)d_in[5];
    const float* b2   = (const float*)d_in[6];
    const float* Wc1  = (const float*)d_in[7];
    const float* bc1  = (const float*)d_in[8];
    const float* Wc2  = (const float*)d_in[9];
    const float* bc2  = (const float*)d_in[10];
    float* out = (float*)d_out;

    const int* src = ei;            // edge_index[0]
    const int* dst = ei + N_EDGES;  // edge_index[1]

    char* ws = (char*)d_ws;
    size_t off = 0;
    auto alloc = [&](size_t bytes) {
        void* p = ws + off;
        off += (bytes + 255) & ~(size_t)255;
        return p;
    };
    unsigned short* hs = (unsigned short*)alloc((size_t)N_NODES * HID * 2);   // 12.8MB bf16
    float* agg     = (float*)alloc((size_t)N_NODES * HID * sizeof(float));    // 25.6MB
    int*   col     = (int*)  alloc((size_t)N_NODES * CAP * sizeof(int) + 256);// 25.6MB padded CSR
    int*   cnt32   = (int*)  alloc((size_t)NSLICE * N_NODES * sizeof(int));   // 12.8MB slice counts
    unsigned char* pos  = (unsigned char*)alloc((size_t)N_EDGES);             // 1.6MB per-edge pos
    unsigned char* off8 = (unsigned char*)alloc((size_t)N_NODES * 32);        // 3.2MB packed bases
    float* dinv    = (float*)alloc(N_NODES * sizeof(float));
    int*   deg     = (int*)  alloc(N_NODES * sizeof(int));
    int*   start   = (int*)  alloc((NG + 1) * sizeof(int));
    unsigned short* W1hi = (unsigned short*)alloc(64 * IN_CH * 2);
    unsigned short* W1lo = (unsigned short*)alloc(64 * IN_CH * 2);
    unsigned short* W2hi = (unsigned short*)alloc(64 * HID * 2);
    unsigned short* W2lo = (unsigned short*)alloc(64 * HID * 2);

    const int TB = 256;

    // weight conversion
    k_wcvt<<<(64 * (IN_CH + HID) + TB - 1) / TB, TB, 0, stream>>>(W1, W2, W1hi, W1lo, W2hi, W2lo);

    // atomic-free CSR build: LDS count (+uchar pos) -> packed base table -> nt place
    k_cntA<<<NXCD * NSLICE, 1024, 0, stream>>>(dst, cnt32, pos);
    k_prep<<<(N_NODES + TB - 1) / TB, TB, 0, stream>>>(cnt32, off8, deg, dinv, col, batch, start);
    k_place<<<(N_EDGES / 2 + TB - 1) / TB, TB, 0, stream>>>(src, dst, pos, off8, col);

    const int gatherBlocks = ((N_NODES + 1) / 2 * 64 + TB - 1) / TB;

    // layer 1
    k_linear<IN_CH><<<LINB, TB, 0, stream>>>(x, W1hi, W1lo, dinv, hs);
    k_gather<<<gatherBlocks, TB, 0, stream>>>(deg, col, (const unsigned int*)hs, dinv, b1, agg);

    // layer 2
    k_linear<HID><<<LINB, TB, 0, stream>>>(agg, W2hi, W2lo, dinv, hs);
    k_gather<<<gatherBlocks, TB, 0, stream>>>(deg, col, (const unsigned int*)hs, dinv, b2, agg);

    // fused mean-pool + head
    k_poolhead<<<NG, 256, 0, stream>>>(agg, start, Wc1, bc1, Wc2, bc2, out);
}

// Round 31
// 188.028 us; speedup vs baseline: 1.1812x; 1.1812x over previous
//
#include <hip/hip_runtime.h>

#define N_NODES 100000
#define N_EDGES 1600000
#define IN_CH   128
#define HID     64
#define NG      256
#define CAP     64   // padded CSR slots per node
#define NXCD    8
#define XRANGE  (N_NODES / NXCD)        // 12500 nodes per range (exact)
#define NSLICE  32
#define PERSLICE (N_EDGES / NSLICE)     // 50000 edges per slice (exact; %4==0)
#define LINB    ((N_NODES + 63) / 64)   // 1563

typedef __attribute__((ext_vector_type(8))) short bf16x8;
typedef __attribute__((ext_vector_type(4))) float f32x4;

// ---- round-to-nearest-even f32 -> bf16 bits ----
__device__ __forceinline__ unsigned short f2bf(float f) {
    union { float f; unsigned u; } v; v.f = f;
    unsigned r = v.u + 0x7FFF + ((v.u >> 16) & 1);
    return (unsigned short)(r >> 16);
}
__device__ __forceinline__ float bfval(unsigned short h) {
    return __uint_as_float((unsigned)h << 16);
}
__device__ __forceinline__ unsigned int f2bf2(float lo, float hi) {
    return (unsigned int)f2bf(lo) | ((unsigned int)f2bf(hi) << 16);
}
__device__ __forceinline__ float bf_lo(unsigned int p) { return __uint_as_float(p << 16); }
__device__ __forceinline__ float bf_hi(unsigned int p) { return __uint_as_float(p & 0xFFFF0000u); }

// ---- W conversion to fragment-linear hi/lo bf16 ----
__global__ void k_wcvt(const float* __restrict__ W1, const float* __restrict__ W2,
                       unsigned short* __restrict__ W1hi, unsigned short* __restrict__ W1lo,
                       unsigned short* __restrict__ W2hi, unsigned short* __restrict__ W2lo) {
    int t = blockIdx.x * blockDim.x + threadIdx.x;
    if (t < 64 * IN_CH) {
        int e = t & 7, lane = (t >> 3) & 63, q = t >> 9;
        int kk = q >> 2, cb = q & 3, kg = lane >> 4, r = lane & 15;
        float v = W1[(kk * 32 + kg * 8 + e) * 64 + cb * 16 + r];
        unsigned short hh = f2bf(v);
        W1hi[t] = hh;
        W1lo[t] = f2bf(v - bfval(hh));
    } else if (t < 64 * IN_CH + 64 * HID) {
        int t2 = t - 64 * IN_CH;
        int e = t2 & 7, lane = (t2 >> 3) & 63, q = t2 >> 9;
        int kk = q >> 2, cb = q & 3, kg = lane >> 4, r = lane & 15;
        float v = W2[(kk * 32 + kg * 8 + e) * 64 + cb * 16 + r];
        unsigned short hh = f2bf(v);
        W2hi[t2] = hh;
        W2lo[t2] = f2bf(v - bfval(hh));
    }
}

// ---- phase A: per-(range,slice) LDS count of dst; per-edge pos via
// PER-ELEMENT byte stores (each edge owned by exactly one range block) ----
__global__ void __launch_bounds__(1024) k_cntA(const int* __restrict__ dst,
                                               int* __restrict__ cnt32,
                                               unsigned char* __restrict__ pos) {
    __shared__ int c[XRANGE];   // 50KB
    const int r = blockIdx.x & (NXCD - 1);
    const int s = blockIdx.x >> 3;
    const int lo = r * XRANGE;
    for (int j = threadIdx.x; j < XRANGE; j += 1024) c[j] = 0;
    __syncthreads();
    const int4* d4 = reinterpret_cast<const int4*>(dst + s * PERSLICE);
    unsigned char* pp = pos + s * PERSLICE;
    for (int q = threadIdx.x; q < PERSLICE / 4; q += 1024) {
        int4 v = d4[q];
        int t, p;
        t = v.x - lo;
        if ((unsigned)t < XRANGE) { p = atomicAdd(&c[t], 1); pp[q * 4 + 0] = (unsigned char)(p < 255 ? p : 255); }
        t = v.y - lo;
        if ((unsigned)t < XRANGE) { p = atomicAdd(&c[t], 1); pp[q * 4 + 1] = (unsigned char)(p < 255 ? p : 255); }
        t = v.z - lo;
        if ((unsigned)t < XRANGE) { p = atomicAdd(&c[t], 1); pp[q * 4 + 2] = (unsigned char)(p < 255 ? p : 255); }
        t = v.w - lo;
        if ((unsigned)t < XRANGE) { p = atomicAdd(&c[t], 1); pp[q * 4 + 3] = (unsigned char)(p < 255 ? p : 255); }
    }
    __syncthreads();
    int* outp = cnt32 + (long)s * N_NODES + lo;
    for (int j = threadIdx.x; j < XRANGE; j += 1024) outp[j] = c[j];
}

// ---- prep: per-node exclusive scan over 32 slice counts -> PACKED uchar
// off8[node][slice] (3.2MB, L2-resident in every XCD); deg, dinv, pad, bounds ----
__global__ void k_prep(const int* __restrict__ cnt32, unsigned char* __restrict__ off8,
                       int* __restrict__ deg, float* __restrict__ dinv,
                       int* __restrict__ col, const int* __restrict__ batch,
                       int* __restrict__ start) {
    int i = blockIdx.x * blockDim.x + threadIdx.x;
    if (i >= N_NODES) return;
    int run = 0;
    unsigned int w[8];
#pragma unroll
    for (int w8 = 0; w8 < 8; ++w8) {
        unsigned int word = 0;
#pragma unroll
        for (int b = 0; b < 4; ++b) {
            int s = w8 * 4 + b;
            int v = cnt32[(long)s * N_NODES + i];
            unsigned int rc = (unsigned int)(run < 255 ? run : 255);
            word |= rc << (8 * b);
            run += v;
        }
        w[w8] = word;
    }
    uint4* o4 = reinterpret_cast<uint4*>(off8 + (long)i * 32);
    o4[0] = (uint4){w[0], w[1], w[2], w[3]};
    o4[1] = (uint4){w[4], w[5], w[6], w[7]};

    deg[i] = run;
    dinv[i] = rsqrtf((float)run + 1.0f);
    int n = run < CAP ? run : CAP;
    int n16 = (n + 15) & ~15;
    int* crow = col + (long)i * CAP;
    int self32 = i * 32;
    for (int p = n; p < n16; ++p) crow[p] = self32;
    int b = batch[i];
    int prev = (i == 0) ? -1 : batch[i - 1];
    for (int g = prev + 1; g <= b; ++g) start[g] = i;
    if (i == N_NODES - 1)
        for (int g = b + 1; g <= NG; ++g) start[g] = N_NODES;
}

// ---- phase C: batched streaming placement, 4 edges/thread (vector loads,
// 4 independent off8 lookups + 4 independent scatter stores in flight) ----
__global__ void k_place(const int* __restrict__ src, const int* __restrict__ dst,
                        const unsigned char* __restrict__ pos,
                        const unsigned char* __restrict__ off8, int* __restrict__ col) {
    int q = blockIdx.x * blockDim.x + threadIdx.x;
    if (q >= N_EDGES / 4) return;
    int4 d = reinterpret_cast<const int4*>(dst)[q];
    int4 u = reinterpret_cast<const int4*>(src)[q];
    uchar4 pq = reinterpret_cast<const uchar4*>(pos)[q];
    int s = (q * 4) / PERSLICE;   // PERSLICE%4==0 -> all 4 edges share slice
    int p0 = (int)off8[(long)d.x * 32 + s] + (int)pq.x;
    int p1 = (int)off8[(long)d.y * 32 + s] + (int)pq.y;
    int p2 = (int)off8[(long)d.z * 32 + s] + (int)pq.z;
    int p3 = (int)off8[(long)d.w * 32 + s] + (int)pq.w;
    if (p0 < CAP) col[(long)d.x * CAP + p0] = u.x * 32;
    if (p1 < CAP) col[(long)d.y * CAP + p1] = u.y * 32;
    if (p2 < CAP) col[(long)d.z * CAP + p2] = u.z * 32;
    if (p3 < CAP) col[(long)d.w * CAP + p3] = u.w * 32;
}

// ---- linear: MFMA GEMM, 32 nodes/wave, frag-linear W, K-split 2-way,
// scaled bf16 out. hs[i][j] = bf16( dinv[i] * sum_k x[i][k]*W[k][j] ) ----
template <int K>
__global__ void __launch_bounds__(256) k_linear(const float* __restrict__ x,
                                                const unsigned short* __restrict__ Whi,
                                                const unsigned short* __restrict__ Wlo,
                                                const float* __restrict__ dinv,
                                                unsigned short* __restrict__ hs) {
    __shared__ f32x4 red[2][64][8];
    const int tid  = threadIdx.x;
    const int wv   = tid >> 6;
    const int pair = wv >> 1;
    const int h    = wv & 1;
    const int lane = tid & 63;
    const int row16 = lane & 15;
    const int kg    = lane >> 4;
    const int n0 = (blockIdx.x * 2 + pair) * 32;
    const bool valid = (n0 < N_NODES);

    f32x4 acc[2][4];
#pragma unroll
    for (int bt = 0; bt < 2; ++bt)
#pragma unroll
        for (int cb = 0; cb < 4; ++cb) acc[bt][cb] = (f32x4){0.f, 0.f, 0.f, 0.f};

    const int NKK = K / 32;
    const int kkBeg = h * (NKK / 2);
    const int kkEnd = kkBeg + NKK / 2;

#pragma unroll
    for (int kk = kkBeg; kk < kkEnd; ++kk) {
        bf16x8 xhi0, xlo0, xhi1, xlo1;
        {
            int rr = n0 + row16;
            rr = rr < N_NODES ? rr : N_NODES - 1;
            const float* ap = x + (long)rr * K + kk * 32 + kg * 8;
            float4 b0 = *reinterpret_cast<const float4*>(ap);
            float4 b1 = *reinterpret_cast<const float4*>(ap + 4);
#define CVT(dsthi, dstlo, i, val) { unsigned short h_ = f2bf(val); dsthi[i] = (short)h_; \
                                    dstlo[i] = (short)f2bf((val) - bfval(h_)); }
            CVT(xhi0, xlo0, 0, b0.x) CVT(xhi0, xlo0, 1, b0.y)
            CVT(xhi0, xlo0, 2, b0.z) CVT(xhi0, xlo0, 3, b0.w)
            CVT(xhi0, xlo0, 4, b1.x) CVT(xhi0, xlo0, 5, b1.y)
            CVT(xhi0, xlo0, 6, b1.z) CVT(xhi0, xlo0, 7, b1.w)
        }
        {
            int rr = n0 + 16 + row16;
            rr = rr < N_NODES ? rr : N_NODES - 1;
            const float* ap = x + (long)rr * K + kk * 32 + kg * 8;
            float4 b0 = *reinterpret_cast<const float4*>(ap);
            float4 b1 = *reinterpret_cast<const float4*>(ap + 4);
            CVT(xhi1, xlo1, 0, b0.x) CVT(xhi1, xlo1, 1, b0.y)
            CVT(xhi1, xlo1, 2, b0.z) CVT(xhi1, xlo1, 3, b0.w)
            CVT(xhi1, xlo1, 4, b1.x) CVT(xhi1, xlo1, 5, b1.y)
            CVT(xhi1, xlo1, 6, b1.z) CVT(xhi1, xlo1, 7, b1.w)
#undef CVT
        }
#pragma unroll
        for (int cb = 0; cb < 4; ++cb) {
            long foff = (long)((kk * 4 + cb) * 64 + lane) * 8;
            bf16x8 wh = *reinterpret_cast<const bf16x8*>(Whi + foff);
            bf16x8 wl = *reinterpret_cast<const bf16x8*>(Wlo + foff);
            acc[0][cb] = __builtin_amdgcn_mfma_f32_16x16x32_bf16(wh, xhi0, acc[0][cb], 0, 0, 0);
            acc[0][cb] = __builtin_amdgcn_mfma_f32_16x16x32_bf16(wh, xlo0, acc[0][cb], 0, 0, 0);
            acc[0][cb] = __builtin_amdgcn_mfma_f32_16x16x32_bf16(wl, xhi0, acc[0][cb], 0, 0, 0);
            acc[1][cb] = __builtin_amdgcn_mfma_f32_16x16x32_bf16(wh, xhi1, acc[1][cb], 0, 0, 0);
            acc[1][cb] = __builtin_amdgcn_mfma_f32_16x16x32_bf16(wh, xlo1, acc[1][cb], 0, 0, 0);
            acc[1][cb] = __builtin_amdgcn_mfma_f32_16x16x32_bf16(wl, xhi1, acc[1][cb], 0, 0, 0);
        }
    }

    if (h == 1) {
#pragma unroll
        for (int bt = 0; bt < 2; ++bt)
#pragma unroll
            for (int cb = 0; cb < 4; ++cb) red[pair][lane][bt * 4 + cb] = acc[bt][cb];
    }
    __syncthreads();
    if (h == 0 && valid) {
#pragma unroll
        for (int bt = 0; bt < 2; ++bt) {
            int n = n0 + bt * 16 + row16;
            float d = dinv[n];
#pragma unroll
            for (int cb = 0; cb < 4; ++cb) {
                f32x4 a = acc[bt][cb];
                f32x4 b = red[pair][lane][bt * 4 + cb];
                uint2 p;
                p.x = f2bf2((a[0] + b[0]) * d, (a[1] + b[1]) * d);
                p.y = f2bf2((a[2] + b[2]) * d, (a[3] + b[3]) * d);
                *reinterpret_cast<uint2*>(&hs[(long)n * 64 + cb * 16 + kg * 4]) = p;
            }
        }
    }
}

// ---- gather: predication-free, col pre-scaled (*32), dense deg ----
__global__ void k_gather(const int* __restrict__ deg, const int* __restrict__ col,
                         const unsigned int* __restrict__ hs2,
                         const float* __restrict__ dinv, const float* __restrict__ bias,
                         float* __restrict__ out) {
    int t = blockIdx.x * blockDim.x + threadIdx.x;
    int lane = t & 63;
    int half = lane >> 5;
    int c2 = lane & 31;
    int i = ((t >> 6) << 1) + half;
    if (i >= N_NODES) return;
    const int4* crow4 = reinterpret_cast<const int4*>(col + (long)i * CAP);
    int n = deg[i];
    n = n < CAP ? n : CAP;
    int n16 = (n + 15) & ~15;
    const unsigned int* hsc = hs2 + c2;
    unsigned int self = hsc[(long)i * 32];
    float selfL = bf_lo(self), selfH = bf_hi(self);
    float aL = selfL, aH = selfH;

    for (int e0 = 0; e0 < n16; e0 += 16) {
        int4 q0 = crow4[(e0 >> 2) + 0];
        int4 q1 = crow4[(e0 >> 2) + 1];
        int4 q2 = crow4[(e0 >> 2) + 2];
        int4 q3 = crow4[(e0 >> 2) + 3];
        unsigned int v[16];
        v[0]  = hsc[(long)q0.x]; v[1]  = hsc[(long)q0.y];
        v[2]  = hsc[(long)q0.z]; v[3]  = hsc[(long)q0.w];
        v[4]  = hsc[(long)q1.x]; v[5]  = hsc[(long)q1.y];
        v[6]  = hsc[(long)q1.z]; v[7]  = hsc[(long)q1.w];
        v[8]  = hsc[(long)q2.x]; v[9]  = hsc[(long)q2.y];
        v[10] = hsc[(long)q2.z]; v[11] = hsc[(long)q2.w];
        v[12] = hsc[(long)q3.x]; v[13] = hsc[(long)q3.y];
        v[14] = hsc[(long)q3.z]; v[15] = hsc[(long)q3.w];
#pragma unroll
        for (int j = 0; j < 16; ++j) {
            aL += bf_lo(v[j]);
            aH += bf_hi(v[j]);
        }
    }
    float fE = (float)(n16 - n);
    aL = fmaf(-fE, selfL, aL);
    aH = fmaf(-fE, selfH, aH);

    float di = dinv[i];
    float vL = fmaf(di, aL, bias[2 * c2]);
    float vH = fmaf(di, aH, bias[2 * c2 + 1]);
    float2 o;
    o.x = vL > 0.f ? vL : 0.f;
    o.y = vH > 0.f ? vH : 0.f;
    *reinterpret_cast<float2*>(&out[(long)i * 64 + 2 * c2]) = o;
}

// ---- fused mean-pool + head MLP ----
__global__ void k_poolhead(const float* __restrict__ a, const int* __restrict__ start,
                           const float* __restrict__ Wc1, const float* __restrict__ bc1,
                           const float* __restrict__ Wc2, const float* __restrict__ bc2,
                           float* __restrict__ out) {
    __shared__ float partial[4][64];
    __shared__ float gvec[64];
    __shared__ float tvec[32];
    int g = blockIdx.x;
    int w = threadIdx.x >> 6;
    int j = threadIdx.x & 63;
    int s0 = start[g], s1 = start[g + 1];
    float acc = 0.f;
    for (int i = s0 + w; i < s1; i += 4)
        acc += a[(long)i * 64 + j];
    partial[w][j] = acc;
    __syncthreads();
    if (w == 0) {
        float c = (float)(s1 - s0);
        c = c > 1.f ? c : 1.f;
        gvec[j] = (partial[0][j] + partial[1][j] + partial[2][j] + partial[3][j]) / c;
    }
    __syncthreads();
    if (threadIdx.x < 32) {
        int jj = threadIdx.x;
        float acc2 = bc1[jj];
#pragma unroll 8
        for (int k = 0; k < 64; ++k) acc2 = fmaf(gvec[k], Wc1[k * 32 + jj], acc2);
        tvec[jj] = acc2 > 0.f ? acc2 : 0.f;
    }
    __syncthreads();
    if (threadIdx.x < 2) {
        int jj = threadIdx.x;
        float acc2 = bc2[jj];
#pragma unroll
        for (int k = 0; k < 32; ++k) acc2 = fmaf(tvec[k], Wc2[k * 2 + jj], acc2);
        out[g * 2 + jj] = acc2;
    }
}

extern "C" void kernel_launch(void* const* d_in, const int* in_sizes, int n_in,
                              void* d_out, int out_size, void* d_ws, size_t ws_size,
                              hipStream_t stream) {
    const float* x    = (const float*)d_in[0];
    const int*   ei   = (const int*)d_in[1];
    const int*   batch= (const int*)d_in[2];
    const float* W1   = (const float*)d_in[3];
    const float* b1   = (const float*)d_in[4];
    const float* W2   = (const float*)d_in[5];
    const float* b2   = (const float*)d_in[6];
    const float* Wc1  = (const float*)d_in[7];
    const float* bc1  = (const float*)d_in[8];
    const float* Wc2  = (const float*)d_in[9];
    const float* bc2  = (const float*)d_in[10];
    float* out = (float*)d_out;

    const int* src = ei;            // edge_index[0]
    const int* dst = ei + N_EDGES;  // edge_index[1]

    char* ws = (char*)d_ws;
    size_t off = 0;
    auto alloc = [&](size_t bytes) {
        void* p = ws + off;
        off += (bytes + 255) & ~(size_t)255;
        return p;
    };
    unsigned short* hs = (unsigned short*)alloc((size_t)N_NODES * HID * 2);   // 12.8MB bf16
    float* agg     = (float*)alloc((size_t)N_NODES * HID * sizeof(float));    // 25.6MB
    int*   col     = (int*)  alloc((size_t)N_NODES * CAP * sizeof(int) + 256);// 25.6MB padded CSR
    int*   cnt32   = (int*)  alloc((size_t)NSLICE * N_NODES * sizeof(int));   // 12.8MB slice counts
    unsigned char* pos  = (unsigned char*)alloc((size_t)N_EDGES);             // 1.6MB per-edge pos
    unsigned char* off8 = (unsigned char*)alloc((size_t)N_NODES * 32);        // 3.2MB packed bases
    float* dinv    = (float*)alloc(N_NODES * sizeof(float));
    int*   deg     = (int*)  alloc(N_NODES * sizeof(int));
    int*   start   = (int*)  alloc((NG + 1) * sizeof(int));
    unsigned short* W1hi = (unsigned short*)alloc(64 * IN_CH * 2);
    unsigned short* W1lo = (unsigned short*)alloc(64 * IN_CH * 2);
    unsigned short* W2hi = (unsigned short*)alloc(64 * HID * 2);
    unsigned short* W2lo = (unsigned short*)alloc(64 * HID * 2);

    const int TB = 256;

    // weight conversion
    k_wcvt<<<(64 * (IN_CH + HID) + TB - 1) / TB, TB, 0, stream>>>(W1, W2, W1hi, W1lo, W2hi, W2lo);

    // atomic-free CSR build: LDS count (+uchar pos) -> packed base table -> batched place
    k_cntA<<<NXCD * NSLICE, 1024, 0, stream>>>(dst, cnt32, pos);
    k_prep<<<(N_NODES + TB - 1) / TB, TB, 0, stream>>>(cnt32, off8, deg, dinv, col, batch, start);
    k_place<<<(N_EDGES / 4 + TB - 1) / TB, TB, 0, stream>>>(src, dst, pos, off8, col);

    const int gatherBlocks = ((N_NODES + 1) / 2 * 64 + TB - 1) / TB;

    // layer 1
    k_linear<IN_CH><<<LINB, TB, 0, stream>>>(x, W1hi, W1lo, dinv, hs);
    k_gather<<<gatherBlocks, TB, 0, stream>>>(deg, col, (const unsigned int*)hs, dinv, b1, agg);

    // layer 2
    k_linear<HID><<<LINB, TB, 0, stream>>>(agg, W2hi, W2lo, dinv, hs);
    k_gather<<<gatherBlocks, TB, 0, stream>>>(deg, col, (const unsigned int*)hs, dinv, b2, agg);

    // fused mean-pool + head
    k_poolhead<<<NG, 256, 0, stream>>>(agg, start, Wc1, bc1, Wc2, bc2, out);
}